// Round 10
// baseline (284.700 us; speedup 1.0000x reference)
//
#include <hip/hip_runtime.h>
#include <math.h>

#define NN 2048
#define NGRAPH 16
#define LG 128
#define LATD 32
#define HIDD 128

typedef __attribute__((ext_vector_type(8))) short short8;
typedef __attribute__((ext_vector_type(4))) float f32x4;

// ---- workspace offsets (floats) ----
#define OFF_XN   0                        // NN*3
#define OFF_HN   (OFF_XN + NN*3)          // NN*32
#define OFF_W2T  (OFF_HN + NN*LATD)       // 3*16384 ushort = 24576 floats
#define OFF_SAB  (OFF_W2T + 24576)        // 32
#define OFF_TB   (OFF_SAB + 32)           // NGRAPH*128
#define OFF_H    (OFF_TB + NGRAPH*HIDD)   // NN*128
#define OFF_XA   (OFF_H + NN*HIDD)        // NN*3
#define OFF_XB   (OFF_XA + NN*3)          // NN*3
#define OFF_PR   (OFF_XB + NN*3)          // NN*128
#define OFF_PCE0 (OFF_PR + NN*HIDD)       // 2*NN*128 ushort = NN*128 floats
#define OFF_PCE1 (OFF_PCE0 + NN*HIDD)     // same
#define OFF_ACC  (OFF_PCE1 + NN*HIDD)     // 4

__device__ __forceinline__ unsigned short f2bf(float f) {
  unsigned u = __float_as_uint(f);
  u += 0x7fffu + ((u >> 16) & 1u);       // RNE
  return (unsigned short)(u >> 16);
}

// Per-graph: alpha_bar cumprod, time-emb fold into in_W1 bias; zeros acc.
__global__ __launch_bounds__(128) void graph_prep_kernel(
    const int* __restrict__ tarr, const float* __restrict__ inW1,
    const float* __restrict__ inb1,
    float* __restrict__ sab, float* __restrict__ tbias, float* __restrict__ acc)
{
  __shared__ float temb[128];
  int g = blockIdx.x;
  int t = threadIdx.x;
  if (g == 0 && t < 4) acc[t] = 0.f;
  int tt = tarr[g];
  float prod = 1.f;
  for (int i=0; i<=tt; ++i) {
    float beta = 1e-4f + 1.99e-4f*(float)i;   // linspace(1e-4, 0.02, 101)
    prod *= (1.f - beta);
  }
  float beta_t = 1e-4f + 1.99e-4f*(float)tt;
  if (t == 0) {
    sab[2*g]   = sqrtf(prod);
    sab[2*g+1] = sqrtf(fmaxf(1.f - prod, 0.f));
  }
  if (t < 64) {
    float freq = __expf(-9.210340371976184f * (float)t / 63.f);  // exp(-ln1e4*t/63)
    float arg = beta_t * freq;
    temb[t]      = sinf(arg);
    temb[t + 64] = cosf(arg);
  }
  __syncthreads();
  float s = inb1[t];
  for (int k=0;k<128;++k) s += temb[k] * inW1[(160+k)*HIDD + t];
  tbias[g*HIDD + t] = s;
}

// Coalesced DDPM noising.
__global__ __launch_bounds__(256) void noise_kernel(
    const float* __restrict__ H0, const float* __restrict__ X0,
    const float* __restrict__ epsH, const float* __restrict__ epsX,
    const int* __restrict__ gmask, const float* __restrict__ sab,
    float* __restrict__ Hn, float* __restrict__ Xn, float* __restrict__ xa)
{
  int idx = blockIdx.x*256 + threadIdx.x;
  if (idx < NN*LATD) {
    int n = idx >> 5;
    int g = n >> 7;
    float sa = sab[2*g], sb = sab[2*g+1];
    float v = H0[idx];
    Hn[idx] = gmask[n] ? sa*v + sb*epsH[idx] : v;
  } else {
    int j = idx - NN*LATD;
    if (j < NN*3) {
      int n = j / 3;
      int g = n >> 7;
      float sa = sab[2*g], sb = sab[2*g+1];
      float v = X0[j];
      float xn = gmask[n] ? sa*v + sb*epsX[j] : v;
      Xn[j] = xn;
      xa[j] = xn;
    }
  }
}

// Transpose + bf16-convert pe_W2 for all 3 layers: w2t[l][col][k].
__global__ __launch_bounds__(128) void w2t_kernel(
    const float* __restrict__ peW2, unsigned short* __restrict__ w2t)
{
  int l = blockIdx.x;
  int t = threadIdx.x;       // col
  const float* W = peW2 + (size_t)l*HIDD*HIDD;
  unsigned* dst = (unsigned*)(w2t + (size_t)l*HIDD*HIDD);
  for (int k2=0; k2<64; ++k2) {
    float v0 = W[(2*k2)*HIDD + t];
    float v1 = W[(2*k2+1)*HIDD + t];
    dst[t*64 + k2] = (unsigned)f2bf(v0) | ((unsigned)f2bf(v1) << 16);
  }
}

// node_init: 3-layer input MLP (tbias-folded) + layer-0 proj (Pr, PcE).
__global__ __launch_bounds__(256) void node_init_kernel(
    const float* __restrict__ Hn, const float* __restrict__ cond,
    const float* __restrict__ tbias, const float* __restrict__ W1,
    const float* __restrict__ W2, const float* __restrict__ b2,
    const float* __restrict__ W3, const float* __restrict__ b3,
    const float* __restrict__ peW1_0, const float* __restrict__ peb1_0,
    const float* __restrict__ eemb,
    float* __restrict__ h, float* __restrict__ Pr, unsigned short* __restrict__ pce)
{
  __shared__ float fL[4][160];
  __shared__ float pbuf[2][4][HIDD];
  __shared__ float h1[4][HIDD];
  __shared__ float h2[4][HIDD];
  __shared__ float hF[4][HIDD];
  int tt = threadIdx.x;
  int nb = blockIdx.x*4;
  int g = nb >> 7;
  int c = tt & 127, half = tt >> 7;
  for (int idx=tt; idx<4*LATD; idx+=256) {
    int nl = idx>>5, k = idx&31;
    fL[nl][k] = Hn[(size_t)nb*LATD + idx];
  }
  for (int idx=tt; idx<4*HIDD; idx+=256) {
    int nl = idx>>7, k = idx&127;
    fL[nl][32+k] = cond[(size_t)nb*HIDD + idx];
  }
  __syncthreads();
  float p[4];
  // layer 1: K=160 split 80/80
  #pragma unroll
  for (int nl=0;nl<4;++nl) p[nl]=0.f;
  for (int k=half*80; k<half*80+80; ++k) {
    float w = W1[k*HIDD+c];
    #pragma unroll
    for (int nl=0;nl<4;++nl) p[nl] += fL[nl][k]*w;
  }
  #pragma unroll
  for (int nl=0;nl<4;++nl) pbuf[half][nl][c] = p[nl];
  __syncthreads();
  {
    float tb = tbias[g*HIDD + c];
    #pragma unroll
    for (int q=0;q<2;++q) {
      int nl = half*2+q;
      h1[nl][c] = fmaxf(tb + pbuf[0][nl][c] + pbuf[1][nl][c], 0.f);
    }
  }
  __syncthreads();
  // layer 2: K=128 split 64/64
  #pragma unroll
  for (int nl=0;nl<4;++nl) p[nl]=0.f;
  for (int k=half*64; k<half*64+64; ++k) {
    float w = W2[k*HIDD+c];
    #pragma unroll
    for (int nl=0;nl<4;++nl) p[nl] += h1[nl][k]*w;
  }
  #pragma unroll
  for (int nl=0;nl<4;++nl) pbuf[half][nl][c] = p[nl];
  __syncthreads();
  #pragma unroll
  for (int q=0;q<2;++q) {
    int nl = half*2+q;
    h2[nl][c] = fmaxf(b2[c] + pbuf[0][nl][c] + pbuf[1][nl][c], 0.f);
  }
  __syncthreads();
  // layer 3: K=128 split 64/64, no relu
  #pragma unroll
  for (int nl=0;nl<4;++nl) p[nl]=0.f;
  for (int k=half*64; k<half*64+64; ++k) {
    float w = W3[k*HIDD+c];
    #pragma unroll
    for (int nl=0;nl<4;++nl) p[nl] += h2[nl][k]*w;
  }
  #pragma unroll
  for (int nl=0;nl<4;++nl) pbuf[half][nl][c] = p[nl];
  __syncthreads();
  #pragma unroll
  for (int q=0;q<2;++q) {
    int nl = half*2+q;
    float v = b3[c] + pbuf[0][nl][c] + pbuf[1][nl][c];
    hF[nl][c] = v;
    h[(size_t)(nb+nl)*HIDD+c] = v;
  }
  __syncthreads();
  // layer-0 proj: which=half (0->Pr, 1->PcE)
  const float* W = peW1_0 + half*HIDD*HIDD;
  float a[4];
  #pragma unroll
  for (int nl=0;nl<4;++nl) a[nl]=0.f;
  for (int k=0;k<HIDD;++k) {
    float w = W[k*HIDD+c];
    #pragma unroll
    for (int nl=0;nl<4;++nl) a[nl] += hF[nl][k]*w;
  }
  if (half == 0) {
    #pragma unroll
    for (int nl=0;nl<4;++nl) Pr[(size_t)(nb+nl)*HIDD+c] = a[nl];
  } else {
    float e0 = peb1_0[c], e1 = peb1_0[c];
    for (int k=0;k<32;++k) {
      float w = peW1_0[(256+k)*HIDD+c];
      e0 += eemb[k]*w;
      e1 += eemb[32+k]*w;
    }
    #pragma unroll
    for (int nl=0;nl<4;++nl) {
      pce[((size_t)(nb+nl))*HIDD + c]      = f2bf(a[nl] + e0);
      pce[((size_t)(NN + nb+nl))*HIDD + c] = f2bf(a[nl] + e1);
    }
  }
}

__device__ __forceinline__ short8 buildA(uint4 p, f32x4 prA, f32x4 prB,
                                         f32x4 wdA, f32x4 wdB, float d2) {
  float s[8];
  unsigned pu[4] = {p.x, p.y, p.z, p.w};
  #pragma unroll
  for (int q=0;q<4;++q) {
    float lo = __uint_as_float(pu[q] << 16);
    float hi = __uint_as_float(pu[q] & 0xffff0000u);
    float pr0 = (q<2) ? prA[2*q]   : prB[2*q-4];
    float pr1 = (q<2) ? prA[2*q+1] : prB[2*q-3];
    float wd0 = (q<2) ? wdA[2*q]   : wdB[2*q-4];
    float wd1 = (q<2) ? wdA[2*q+1] : wdB[2*q-3];
    s[2*q]   = fmaxf(pr0 + lo + d2*wd0, 0.f);
    s[2*q+1] = fmaxf(pr1 + hi + d2*wd1, 0.f);
  }
  uint4 r;
  asm("v_cvt_pk_bf16_f32 %0, %1, %2" : "=v"(r.x) : "v"(s[0]), "v"(s[1]));
  asm("v_cvt_pk_bf16_f32 %0, %1, %2" : "=v"(r.y) : "v"(s[2]), "v"(s[3]));
  asm("v_cvt_pk_bf16_f32 %0, %1, %2" : "=v"(r.z) : "v"(s[4]), "v"(s[5]));
  asm("v_cvt_pk_bf16_f32 %0, %1, %2" : "=v"(r.w) : "v"(s[6]), "v"(s[7]));
  return *(short8*)&r;
}

// Fused layer kernel: 256 threads = 4 waves, 2 i-rows/block, grid 1024.
// Wave wv = (iLocal=wv>>1, jhalf=wv&1) — same inner loop / live set as the
// proven r7 kernel (84 VGPR, no spill), but 2x the grid -> 3 blocks/CU.
// ROUND-8/9 LESSON: 512-thread blocks make the allocator clamp to 64 VGPR
// and spill acc to scratch (91-415 MB HBM/dispatch). Stay at 256 threads.
template<bool NEXT>
__global__ __launch_bounds__(256, 3) void layer_kernel(
    const float* __restrict__ xR, float* __restrict__ xW,
    float* __restrict__ Pr,
    const unsigned short* __restrict__ pceR, unsigned short* __restrict__ pceW,
    const unsigned short* __restrict__ w2t,
    const float* __restrict__ peW1l, const float* __restrict__ peb2l,
    const float* __restrict__ pxWl, const float* __restrict__ pxbl,
    float* __restrict__ hbuf,
    const float* __restrict__ phW1l, const float* __restrict__ phb1l,
    const float* __restrict__ phW2l, const float* __restrict__ phb2l,
    const float* __restrict__ peW1n, const float* __restrict__ peb1n,
    const float* __restrict__ eemb, const int* __restrict__ lengths)
{
  __shared__ __align__(16) unsigned short W2s[HIDD*HIDD];  // 32 KB, swizzled
  __shared__ __align__(16) float PrL[2][HIDD];
  __shared__ __align__(16) float W1dL[HIDD];
  __shared__ float b2L[HIDD];
  __shared__ float pxWL[HIDD];
  __shared__ float xgL[LG][3];
  __shared__ float SxL[3];
  __shared__ float aggAll[2][HIDD];
  __shared__ float xmP[4][3];
  __shared__ float hL[2][HIDD];        // in-place updated h
  __shared__ float uL[2][HIDD];
  __shared__ float partU[2][2][HIDD];
  __shared__ float EFbL[2][HIDD];

  int tt = threadIdx.x;
  int bid = blockIdx.x;
  int g = bid >> 6, ip = bid & 63;
  int i0 = ip*2;
  int nbase = g*LG;

  int wv = tt >> 6, l = tt & 63;
  int l15 = l & 15, lg2 = l >> 4;
  int iLocal = wv >> 1, jh = wv & 1;
  int i = i0 + iLocal;

  // stage W2^T -> LDS with XOR swizzle (byte ^= (col&7)<<4)
  {
    int col = tt & 127, kh = tt >> 7;
    const uint4* src = (const uint4*)(w2t + (size_t)col*HIDD + kh*64);
    #pragma unroll
    for (int c8=0;c8<8;++c8) {
      uint4 v = src[c8];
      int koff2 = (kh*64 + c8*8)*2;
      int byteoff = col*256 + (koff2 ^ ((col&7)<<4));
      *(uint4*)((char*)W2s + byteoff) = v;
    }
  }
  if (tt < HIDD) {
    W1dL[tt] = peW1l[288*HIDD + tt];
    b2L[tt]  = peb2l[tt];
    pxWL[tt] = pxWl[tt];
  }
  for (int idx=tt; idx<LG*3; idx+=256)
    ((float*)xgL)[idx] = xR[(size_t)nbase*3 + idx];
  {
    int pr_n = tt >> 7, pr_c = tt & 127;
    PrL[pr_n][pr_c] = Pr[(size_t)(nbase + i0 + pr_n)*HIDD + pr_c];
    aggAll[pr_n][pr_c] = 0.f;
  }
  __syncthreads();
  if (tt < 3) {
    float s = 0.f;
    for (int j=0;j<LG;++j) s += xgL[j][tt];
    SxL[tt] = s;
  }
  float pxb0 = pxbl[0];

  // ---- Phase A: wave wv = (iLocal, jh): i over 64 j (2 jp-pairs) ----
  float xi0 = xgL[i][0], xi1 = xgL[i][1], xi2 = xgL[i][2];
  int ci = (i >= 64) ? 1 : 0;
  float colsum[8];
  #pragma unroll
  for (int cf=0;cf<8;++cf) colsum[cf] = 0.f;
  float xmx = 0.f, xmy = 0.f, xmz = 0.f;

  for (int jj=0; jj<2; ++jj) {
    int jp = jh*2 + jj;
    int j0 = jp*32 + l15, j1 = j0 + 16;
    float dxa = xi0 - xgL[j0][0], dya = xi1 - xgL[j0][1], dza = xi2 - xgL[j0][2];
    float d2a = dxa*dxa + dya*dya + dza*dza;
    float dxb = xi0 - xgL[j1][0], dyb = xi1 - xgL[j1][1], dzb = xi2 - xgL[j1][2];
    float d2b = dxb*dxb + dyb*dyb + dzb*dzb;
    int et0 = (ci != ((j0 >= 64) ? 1 : 0)) ? 1 : 0;
    int et1 = (ci != ((j1 >= 64) ? 1 : 0)) ? 1 : 0;
    const unsigned short* pceB0 = pceR + ((size_t)(et0*NN + nbase + j0))*HIDD;
    const unsigned short* pceB1 = pceR + ((size_t)(et1*NN + nbase + j1))*HIDD;

    short8 a0[4], a1[4];
    #pragma unroll
    for (int kk=0;kk<4;++kk) {
      int ks = kk*32 + lg2*8;
      f32x4 prA = *(const f32x4*)&PrL[iLocal][ks];
      f32x4 prB = *(const f32x4*)&PrL[iLocal][ks+4];
      f32x4 wdA = *(const f32x4*)&W1dL[ks];
      f32x4 wdB = *(const f32x4*)&W1dL[ks+4];
      uint4 pa = *(const uint4*)(pceB0 + ks);
      uint4 pb = *(const uint4*)(pceB1 + ks);
      a0[kk] = buildA(pa, prA, prB, wdA, wdB, d2a);
      a1[kk] = buildA(pb, prA, prB, wdA, wdB, d2b);
    }

    f32x4 zz = {0.f,0.f,0.f,0.f};
    f32x4 acc[2][8];
    #pragma unroll
    for (int r=0;r<2;++r)
      #pragma unroll
      for (int cf=0;cf<8;++cf) acc[r][cf] = zz;

    #pragma unroll
    for (int kk=0;kk<4;++kk) {
      int kbyte = kk*64 + lg2*16;
      #pragma unroll
      for (int cf=0;cf<8;++cf) {
        int col = cf*16 + l15;
        int boff = col*256 + (kbyte ^ ((col&7)<<4));
        short8 bF = *(const short8*)((const char*)W2s + boff);
        acc[0][cf] = __builtin_amdgcn_mfma_f32_16x16x32_bf16(a0[kk], bF, acc[0][cf], 0,0,0);
        acc[1][cf] = __builtin_amdgcn_mfma_f32_16x16x32_bf16(a1[kk], bF, acc[1][cf], 0,0,0);
      }
    }

    // epilogue: m = relu(acc + b2); colsum[cf] += m; px row-dots -> xm
    float pxp[2][4];
    #pragma unroll
    for (int r=0;r<2;++r)
      #pragma unroll
      for (int q=0;q<4;++q) pxp[r][q] = 0.f;
    #pragma unroll
    for (int cf=0;cf<8;++cf) {
      int col = cf*16 + l15;
      float b2v = b2L[col], pxv = pxWL[col];
      #pragma unroll
      for (int r=0;r<2;++r)
        #pragma unroll
        for (int q=0;q<4;++q) {
          float m = fmaxf(acc[r][cf][q] + b2v, 0.f);
          colsum[cf] += m;
          pxp[r][q] += m * pxv;
        }
    }
    #pragma unroll
    for (int r=0;r<2;++r)
      #pragma unroll
      for (int q=0;q<4;++q) {
        int row = jp*32 + r*16 + lg2*4 + q;   // C/D row mapping (m89)
        float p = pxp[r][q];
        xmx += p*(xi0 - xgL[row][0]);
        xmy += p*(xi1 - xgL[row][1]);
        xmz += p*(xi2 - xgL[row][2]);
      }
  }

  // agg: reduce over lg2 groups; 2-way contention across jh waves
  #pragma unroll
  for (int cf=0;cf<8;++cf) {
    float v = colsum[cf];
    v += __shfl_xor(v, 16);
    v += __shfl_xor(v, 32);
    if (l < 16) atomicAdd(&aggAll[iLocal][cf*16 + l15], v);
  }
  #pragma unroll
  for (int s=1; s<64; s<<=1) {
    xmx += __shfl_xor(xmx, s);
    xmy += __shfl_xor(xmy, s);
    xmz += __shfl_xor(xmz, s);
  }
  if (l == 0) { xmP[wv][0] = xmx; xmP[wv][1] = xmy; xmP[wv][2] = xmz; }

  // ---- Phase B: 2 nodes x (128 ch x 2 K-halves) ----
  int c = tt & 127, half = tt >> 7;
  {
    int hl_n = tt >> 7, hl_c = tt & 127;
    hL[hl_n][hl_c] = hbuf[(size_t)(nbase + i0 + hl_n)*HIDD + hl_c];
  }
  if (NEXT) {
    int e = half;
    float s = peb1n[c];
    for (int k=0;k<32;++k) s += eemb[e*32+k]*peW1n[(256+k)*HIDD+c];
    EFbL[e][c] = s;
  }
  __syncthreads();   // aggAll atomics done; hL loaded

  float p[2];
  // GEMM1: u_pre = [h|agg] @ ph_W1, K=256 split by half
  {
    const float (*cat)[HIDD] = half ? aggAll : hL;
    p[0] = 0.f; p[1] = 0.f;
    const float* Wb = phW1l + (size_t)(half*HIDD)*HIDD + c;
    for (int k=0;k<HIDD;++k) {
      float wvv = Wb[k*HIDD];
      p[0] += cat[0][k]*wvv;
      p[1] += cat[1][k]*wvv;
    }
    partU[half][0][c] = p[0];
    partU[half][1][c] = p[1];
  }
  __syncthreads();
  {
    int nl = tt >> 7, cc = tt & 127;
    uL[nl][cc] = fmaxf(phb1l[cc] + partU[0][nl][cc] + partU[1][nl][cc], 0.f);
  }
  __syncthreads();
  // GEMM2: du = u @ ph_W2, K=128 split 64/64
  {
    p[0] = 0.f; p[1] = 0.f;
    const float* Wb = phW2l + (size_t)(half*64)*HIDD + c;
    for (int k=0;k<64;++k) {
      float wvv = Wb[k*HIDD];
      p[0] += uL[0][half*64+k]*wvv;
      p[1] += uL[1][half*64+k]*wvv;
    }
    partU[half][0][c] = p[0];
    partU[half][1][c] = p[1];
  }
  __syncthreads();
  {
    int nl = tt >> 7, cc = tt & 127;
    float hn = hL[nl][cc] + phb2l[cc] + partU[0][nl][cc] + partU[1][nl][cc];
    hL[nl][cc] = hn;                                   // in-place update
    hbuf[(size_t)(nbase+i0+nl)*HIDD+cc] = hn;
  }
  __syncthreads();
  if (NEXT) {
    const float* W = peW1n + (size_t)half*HIDD*HIDD;
    float a[2];
    a[0] = 0.f; a[1] = 0.f;
    for (int k=0;k<HIDD;++k) {
      float wvv = W[k*HIDD+c];
      a[0] += hL[0][k]*wvv;
      a[1] += hL[1][k]*wvv;
    }
    if (half == 0) {
      #pragma unroll
      for (int q=0;q<2;++q) Pr[(size_t)(nbase+i0+q)*HIDD+c] = a[q];
    } else {
      float e0 = EFbL[0][c], e1 = EFbL[1][c];
      #pragma unroll
      for (int q=0;q<2;++q) {
        pceW[((size_t)(nbase+i0+q))*HIDD + c]      = f2bf(a[q] + e0);
        pceW[((size_t)(NN + nbase+i0+q))*HIDD + c] = f2bf(a[q] + e1);
      }
    }
  }
  // x update (xm partials + analytic pxb term), ping-pong write
  if (tt < 6) {
    int nl = tt/3, cc = tt%3;
    int ii = i0 + nl;
    float deg = (float)lengths[g];
    float xmv = xmP[2*nl][cc] + xmP[2*nl+1][cc] + pxb0*(128.f*xgL[ii][cc] - SxL[cc]);
    xW[(size_t)(nbase+ii)*3 + cc] = xgL[ii][cc] + xmv/deg;
  }
}

__global__ __launch_bounds__(256) void loss_kernel(
    const float* __restrict__ h, const float* __restrict__ h2iW,
    const float* __restrict__ h2ib, const float* __restrict__ Hn,
    const float* __restrict__ Xn, const float* __restrict__ xf,
    const float* __restrict__ epsH, const float* __restrict__ epsX,
    const int* __restrict__ gmask, float* __restrict__ acc)
{
  __shared__ float hL[8][HIDD];
  __shared__ float rX[256], rH[256], rC[256];
  int tt = threadIdx.x;
  int nb = blockIdx.x*8;
  for (int idx=tt; idx<8*HIDD; idx+=256)
    ((float*)hL)[idx] = h[(size_t)nb*HIDD + idx];
  __syncthreads();
  int nl = tt>>5, c = tt&31;
  int n = nb+nl;
  float mf = gmask[n] ? 1.f : 0.f;
  float pj = h2ib[c];
  for (int k=0;k<HIDD;++k) pj += hL[nl][k]*h2iW[k*LATD+c];
  float dH = mf*((pj - Hn[n*LATD+c]) - epsH[n*LATD+c]);
  float sH = dH*dH;
  float sX = 0.f, sc = 0.f;
  if (c < 3) {
    float dX = mf*((xf[n*3+c]-Xn[n*3+c]) - epsX[n*3+c]);
    sX = dX*dX;
  }
  if (c == 0) sc = mf;
  rX[tt]=sX; rH[tt]=sH; rC[tt]=sc;
  __syncthreads();
  for (int s=128; s>0; s>>=1) {
    if (tt<s) { rX[tt]+=rX[tt+s]; rH[tt]+=rH[tt+s]; rC[tt]+=rC[tt+s]; }
    __syncthreads();
  }
  if (tt==0) {
    atomicAdd(&acc[0], rX[0]);
    atomicAdd(&acc[1], rH[0]);
    atomicAdd(&acc[2], rC[0]);
  }
}

__global__ void finalize_kernel(const float* __restrict__ acc, float* __restrict__ out) {
  if (threadIdx.x==0) {
    float cnt = acc[2] + 1e-8f;
    out[0] = acc[0]/cnt;
    out[1] = acc[1]/cnt;
  }
}

extern "C" void kernel_launch(void* const* d_in, const int* in_sizes, int n_in,
                              void* d_out, int out_size, void* d_ws, size_t ws_size,
                              hipStream_t stream) {
  (void)in_sizes; (void)n_in; (void)out_size; (void)ws_size;
  const float* H0    = (const float*)d_in[0];
  const float* X0    = (const float*)d_in[1];
  const float* cond  = (const float*)d_in[2];
  const float* epsH  = (const float*)d_in[3];
  const float* epsX  = (const float*)d_in[4];
  const float* inW1  = (const float*)d_in[5];
  const float* inb1  = (const float*)d_in[6];
  const float* inW2  = (const float*)d_in[7];
  const float* inb2  = (const float*)d_in[8];
  const float* inW3  = (const float*)d_in[9];
  const float* inb3  = (const float*)d_in[10];
  const float* eemb  = (const float*)d_in[11];
  const float* h2iW  = (const float*)d_in[12];
  const float* h2ib  = (const float*)d_in[13];
  const float* peW1  = (const float*)d_in[14];
  const float* peb1  = (const float*)d_in[15];
  const float* peW2  = (const float*)d_in[16];
  const float* peb2  = (const float*)d_in[17];
  const float* phW1  = (const float*)d_in[18];
  const float* phb1  = (const float*)d_in[19];
  const float* phW2  = (const float*)d_in[20];
  const float* phb2  = (const float*)d_in[21];
  const float* pxW   = (const float*)d_in[22];
  const float* pxB   = (const float*)d_in[23];
  const int* gmask   = (const int*)d_in[24];
  const int* batch   = (const int*)d_in[25];
  (void)batch;
  // d_in[26] edges, d_in[27] edge_types: deterministic (dense per-graph meshgrid,
  // et = chain(i)!=chain(j), chain = local>=64) — recomputed on the fly.
  const int* lengths = (const int*)d_in[28];
  const int* tarr    = (const int*)d_in[29];

  float* ws  = (float*)d_ws;
  float* out = (float*)d_out;
  float* Xn   = ws + OFF_XN;
  float* Hn   = ws + OFF_HN;
  unsigned short* w2tb = (unsigned short*)(ws + OFF_W2T);
  float* sabb = ws + OFF_SAB;
  float* tbb  = ws + OFF_TB;
  float* hbuf = ws + OFF_H;
  float* Xa   = ws + OFF_XA;
  float* Xb   = ws + OFF_XB;
  float* Prb  = ws + OFF_PR;
  unsigned short* pce0 = (unsigned short*)(ws + OFF_PCE0);
  unsigned short* pce1 = (unsigned short*)(ws + OFF_PCE1);
  float* accb = ws + OFF_ACC;

  graph_prep_kernel<<<NGRAPH, 128, 0, stream>>>(tarr, inW1, inb1, sabb, tbb, accb);
  noise_kernel<<<(NN*LATD + NN*3 + 255)/256, 256, 0, stream>>>(
      H0, X0, epsH, epsX, gmask, sabb, Hn, Xn, Xa);
  w2t_kernel<<<3, 128, 0, stream>>>(peW2, w2tb);
  node_init_kernel<<<NN/4, 256, 0, stream>>>(
      Hn, cond, tbb, inW1, inW2, inb2, inW3, inb3,
      peW1, peb1, eemb, hbuf, Prb, pce0);

  // l=0: x: Xa->Xb, pce: 0->1 (proj for layer 1)
  layer_kernel<true><<<NGRAPH*64, 256, 0, stream>>>(
      Xa, Xb, Prb, pce0, pce1, w2tb + 0*(size_t)HIDD*HIDD,
      peW1 + 0*(size_t)289*HIDD, peb2 + 0*HIDD, pxW + 0*HIDD, pxB + 0,
      hbuf, phW1 + 0*(size_t)256*HIDD, phb1 + 0*HIDD,
      phW2 + 0*(size_t)HIDD*HIDD, phb2 + 0*HIDD,
      peW1 + 1*(size_t)289*HIDD, peb1 + 1*HIDD, eemb, lengths);
  // l=1: x: Xb->Xa, pce: 1->0 (proj for layer 2)
  layer_kernel<true><<<NGRAPH*64, 256, 0, stream>>>(
      Xb, Xa, Prb, pce1, pce0, w2tb + 1*(size_t)HIDD*HIDD,
      peW1 + 1*(size_t)289*HIDD, peb2 + 1*HIDD, pxW + 1*HIDD, pxB + 1,
      hbuf, phW1 + 1*(size_t)256*HIDD, phb1 + 1*HIDD,
      phW2 + 1*(size_t)HIDD*HIDD, phb2 + 1*HIDD,
      peW1 + 2*(size_t)289*HIDD, peb1 + 2*HIDD, eemb, lengths);
  // l=2: x: Xa->Xb, no next proj
  layer_kernel<false><<<NGRAPH*64, 256, 0, stream>>>(
      Xa, Xb, Prb, pce0, nullptr, w2tb + 2*(size_t)HIDD*HIDD,
      peW1 + 2*(size_t)289*HIDD, peb2 + 2*HIDD, pxW + 2*HIDD, pxB + 2,
      hbuf, phW1 + 2*(size_t)256*HIDD, phb1 + 2*HIDD,
      phW2 + 2*(size_t)HIDD*HIDD, phb2 + 2*HIDD,
      nullptr, nullptr, eemb, lengths);

  loss_kernel<<<NN/8, 256, 0, stream>>>(hbuf, h2iW, h2ib, Hn, Xn, Xb,
                                        epsH, epsX, gmask, accb);
  finalize_kernel<<<1, 64, 0, stream>>>(accb, out);
}

// Round 11
// 272.935 us; speedup vs baseline: 1.0431x; 1.0431x over previous
//
#include <hip/hip_runtime.h>
#include <math.h>

#define NN 2048
#define NGRAPH 16
#define LG 128
#define LATD 32
#define HIDD 128

typedef __attribute__((ext_vector_type(8))) short short8;
typedef __attribute__((ext_vector_type(4))) float f32x4;

// ---- workspace offsets (floats) ----
#define OFF_XN   0                        // NN*3
#define OFF_HN   (OFF_XN + NN*3)          // NN*32
#define OFF_W2T  (OFF_HN + NN*LATD)       // 3*16384 ushort = 24576 floats
#define OFF_SAB  (OFF_W2T + 24576)        // 32
#define OFF_TB   (OFF_SAB + 32)           // NGRAPH*128
#define OFF_H    (OFF_TB + NGRAPH*HIDD)   // NN*128
#define OFF_XA   (OFF_H + NN*HIDD)        // NN*3
#define OFF_XB   (OFF_XA + NN*3)          // NN*3
#define OFF_PR   (OFF_XB + NN*3)          // NN*128
#define OFF_PCE0 (OFF_PR + NN*HIDD)       // 2*NN*128 ushort = NN*128 floats
#define OFF_PCE1 (OFF_PCE0 + NN*HIDD)     // same
#define OFF_ACC  (OFF_PCE1 + NN*HIDD)     // 4

__device__ __forceinline__ unsigned short f2bf(float f) {
  unsigned u = __float_as_uint(f);
  u += 0x7fffu + ((u >> 16) & 1u);       // RNE
  return (unsigned short)(u >> 16);
}

// Per-graph: alpha_bar cumprod, time-emb fold into in_W1 bias; zeros acc.
__global__ __launch_bounds__(128) void graph_prep_kernel(
    const int* __restrict__ tarr, const float* __restrict__ inW1,
    const float* __restrict__ inb1,
    float* __restrict__ sab, float* __restrict__ tbias, float* __restrict__ acc)
{
  __shared__ float temb[128];
  int g = blockIdx.x;
  int t = threadIdx.x;
  if (g == 0 && t < 4) acc[t] = 0.f;
  int tt = tarr[g];
  float prod = 1.f;
  for (int i=0; i<=tt; ++i) {
    float beta = 1e-4f + 1.99e-4f*(float)i;   // linspace(1e-4, 0.02, 101)
    prod *= (1.f - beta);
  }
  float beta_t = 1e-4f + 1.99e-4f*(float)tt;
  if (t == 0) {
    sab[2*g]   = sqrtf(prod);
    sab[2*g+1] = sqrtf(fmaxf(1.f - prod, 0.f));
  }
  if (t < 64) {
    float freq = __expf(-9.210340371976184f * (float)t / 63.f);  // exp(-ln1e4*t/63)
    float arg = beta_t * freq;
    temb[t]      = sinf(arg);
    temb[t + 64] = cosf(arg);
  }
  __syncthreads();
  float s = inb1[t];
  #pragma unroll 8
  for (int k=0;k<128;++k) s += temb[k] * inW1[(160+k)*HIDD + t];
  tbias[g*HIDD + t] = s;
}

// Coalesced DDPM noising.
__global__ __launch_bounds__(256) void noise_kernel(
    const float* __restrict__ H0, const float* __restrict__ X0,
    const float* __restrict__ epsH, const float* __restrict__ epsX,
    const int* __restrict__ gmask, const float* __restrict__ sab,
    float* __restrict__ Hn, float* __restrict__ Xn, float* __restrict__ xa)
{
  int idx = blockIdx.x*256 + threadIdx.x;
  if (idx < NN*LATD) {
    int n = idx >> 5;
    int g = n >> 7;
    float sa = sab[2*g], sb = sab[2*g+1];
    float v = H0[idx];
    Hn[idx] = gmask[n] ? sa*v + sb*epsH[idx] : v;
  } else {
    int j = idx - NN*LATD;
    if (j < NN*3) {
      int n = j / 3;
      int g = n >> 7;
      float sa = sab[2*g], sb = sab[2*g+1];
      float v = X0[j];
      float xn = gmask[n] ? sa*v + sb*epsX[j] : v;
      Xn[j] = xn;
      xa[j] = xn;
    }
  }
}

// Transpose + bf16-convert pe_W2 for all 3 layers: w2t[l][col][k].
__global__ __launch_bounds__(128) void w2t_kernel(
    const float* __restrict__ peW2, unsigned short* __restrict__ w2t)
{
  int l = blockIdx.x;
  int t = threadIdx.x;       // col
  const float* W = peW2 + (size_t)l*HIDD*HIDD;
  unsigned* dst = (unsigned*)(w2t + (size_t)l*HIDD*HIDD);
  #pragma unroll 4
  for (int k2=0; k2<64; ++k2) {
    float v0 = W[(2*k2)*HIDD + t];
    float v1 = W[(2*k2+1)*HIDD + t];
    dst[t*64 + k2] = (unsigned)f2bf(v0) | ((unsigned)f2bf(v1) << 16);
  }
}

// node_init: 3-layer input MLP (tbias-folded) + layer-0 proj (Pr, PcE).
__global__ __launch_bounds__(256) void node_init_kernel(
    const float* __restrict__ Hn, const float* __restrict__ cond,
    const float* __restrict__ tbias, const float* __restrict__ W1,
    const float* __restrict__ W2, const float* __restrict__ b2,
    const float* __restrict__ W3, const float* __restrict__ b3,
    const float* __restrict__ peW1_0, const float* __restrict__ peb1_0,
    const float* __restrict__ eemb,
    float* __restrict__ h, float* __restrict__ Pr, unsigned short* __restrict__ pce)
{
  __shared__ float fL[4][160];
  __shared__ float pbuf[2][4][HIDD];
  __shared__ float h1[4][HIDD];
  __shared__ float h2[4][HIDD];
  __shared__ float hF[4][HIDD];
  int tt = threadIdx.x;
  int nb = blockIdx.x*4;
  int g = nb >> 7;
  int c = tt & 127, half = tt >> 7;
  for (int idx=tt; idx<4*LATD; idx+=256) {
    int nl = idx>>5, k = idx&31;
    fL[nl][k] = Hn[(size_t)nb*LATD + idx];
  }
  for (int idx=tt; idx<4*HIDD; idx+=256) {
    int nl = idx>>7, k = idx&127;
    fL[nl][32+k] = cond[(size_t)nb*HIDD + idx];
  }
  __syncthreads();
  float p[4];
  // layer 1: K=160 split 80/80
  #pragma unroll
  for (int nl=0;nl<4;++nl) p[nl]=0.f;
  {
    int kb = half*80;
    #pragma unroll 8
    for (int k=kb; k<kb+80; ++k) {
      float w = W1[k*HIDD+c];
      #pragma unroll
      for (int nl=0;nl<4;++nl) p[nl] += fL[nl][k]*w;
    }
  }
  #pragma unroll
  for (int nl=0;nl<4;++nl) pbuf[half][nl][c] = p[nl];
  __syncthreads();
  {
    float tb = tbias[g*HIDD + c];
    #pragma unroll
    for (int q=0;q<2;++q) {
      int nl = half*2+q;
      h1[nl][c] = fmaxf(tb + pbuf[0][nl][c] + pbuf[1][nl][c], 0.f);
    }
  }
  __syncthreads();
  // layer 2: K=128 split 64/64
  #pragma unroll
  for (int nl=0;nl<4;++nl) p[nl]=0.f;
  {
    int kb = half*64;
    #pragma unroll 8
    for (int k=kb; k<kb+64; ++k) {
      float w = W2[k*HIDD+c];
      #pragma unroll
      for (int nl=0;nl<4;++nl) p[nl] += h1[nl][k]*w;
    }
  }
  #pragma unroll
  for (int nl=0;nl<4;++nl) pbuf[half][nl][c] = p[nl];
  __syncthreads();
  #pragma unroll
  for (int q=0;q<2;++q) {
    int nl = half*2+q;
    h2[nl][c] = fmaxf(b2[c] + pbuf[0][nl][c] + pbuf[1][nl][c], 0.f);
  }
  __syncthreads();
  // layer 3: K=128 split 64/64, no relu
  #pragma unroll
  for (int nl=0;nl<4;++nl) p[nl]=0.f;
  {
    int kb = half*64;
    #pragma unroll 8
    for (int k=kb; k<kb+64; ++k) {
      float w = W3[k*HIDD+c];
      #pragma unroll
      for (int nl=0;nl<4;++nl) p[nl] += h2[nl][k]*w;
    }
  }
  #pragma unroll
  for (int nl=0;nl<4;++nl) pbuf[half][nl][c] = p[nl];
  __syncthreads();
  #pragma unroll
  for (int q=0;q<2;++q) {
    int nl = half*2+q;
    float v = b3[c] + pbuf[0][nl][c] + pbuf[1][nl][c];
    hF[nl][c] = v;
    h[(size_t)(nb+nl)*HIDD+c] = v;
  }
  __syncthreads();
  // layer-0 proj: which=half (0->Pr, 1->PcE)
  const float* W = peW1_0 + half*HIDD*HIDD;
  float a[4];
  #pragma unroll
  for (int nl=0;nl<4;++nl) a[nl]=0.f;
  #pragma unroll 8
  for (int k=0;k<HIDD;++k) {
    float w = W[k*HIDD+c];
    #pragma unroll
    for (int nl=0;nl<4;++nl) a[nl] += hF[nl][k]*w;
  }
  if (half == 0) {
    #pragma unroll
    for (int nl=0;nl<4;++nl) Pr[(size_t)(nb+nl)*HIDD+c] = a[nl];
  } else {
    float e0 = peb1_0[c], e1 = peb1_0[c];
    #pragma unroll 8
    for (int k=0;k<32;++k) {
      float w = peW1_0[(256+k)*HIDD+c];
      e0 += eemb[k]*w;
      e1 += eemb[32+k]*w;
    }
    #pragma unroll
    for (int nl=0;nl<4;++nl) {
      pce[((size_t)(nb+nl))*HIDD + c]      = f2bf(a[nl] + e0);
      pce[((size_t)(NN + nb+nl))*HIDD + c] = f2bf(a[nl] + e1);
    }
  }
}

__device__ __forceinline__ short8 buildA(uint4 p, f32x4 prA, f32x4 prB,
                                         f32x4 wdA, f32x4 wdB, float d2) {
  float s[8];
  unsigned pu[4] = {p.x, p.y, p.z, p.w};
  #pragma unroll
  for (int q=0;q<4;++q) {
    float lo = __uint_as_float(pu[q] << 16);
    float hi = __uint_as_float(pu[q] & 0xffff0000u);
    float pr0 = (q<2) ? prA[2*q]   : prB[2*q-4];
    float pr1 = (q<2) ? prA[2*q+1] : prB[2*q-3];
    float wd0 = (q<2) ? wdA[2*q]   : wdB[2*q-4];
    float wd1 = (q<2) ? wdA[2*q+1] : wdB[2*q-3];
    s[2*q]   = fmaxf(pr0 + lo + d2*wd0, 0.f);
    s[2*q+1] = fmaxf(pr1 + hi + d2*wd1, 0.f);
  }
  uint4 r;
  asm("v_cvt_pk_bf16_f32 %0, %1, %2" : "=v"(r.x) : "v"(s[0]), "v"(s[1]));
  asm("v_cvt_pk_bf16_f32 %0, %1, %2" : "=v"(r.y) : "v"(s[2]), "v"(s[3]));
  asm("v_cvt_pk_bf16_f32 %0, %1, %2" : "=v"(r.z) : "v"(s[4]), "v"(s[5]));
  asm("v_cvt_pk_bf16_f32 %0, %1, %2" : "=v"(r.w) : "v"(s[6]), "v"(s[7]));
  return *(short8*)&r;
}

// Fused layer kernel (r7 structure: 256 thr, 4 i/block, grid 512, wave owns i).
// NEW vs r7: (a) pce rows staged in LDS once per block (4x reuse, phase A is
// pure LDS+MFMA — no global loads in the inner loop); (b) phase-B K-loops
// unrolled x8 to hide L2 latency; (c) pceL unioned with phase-B scratch.
// ROUND-8/9 LESSON: 512-thread blocks clamp VGPR to 64 and spill acc. Stay 256.
template<bool NEXT>
__global__ __launch_bounds__(256, 3) void layer_kernel(
    const float* __restrict__ xR, float* __restrict__ xW,
    float* __restrict__ Pr,
    const unsigned short* __restrict__ pceR, unsigned short* __restrict__ pceW,
    const unsigned short* __restrict__ w2t,
    const float* __restrict__ peW1l, const float* __restrict__ peb2l,
    const float* __restrict__ pxWl, const float* __restrict__ pxbl,
    float* __restrict__ hbuf,
    const float* __restrict__ phW1l, const float* __restrict__ phb1l,
    const float* __restrict__ phW2l, const float* __restrict__ phb2l,
    const float* __restrict__ peW1n, const float* __restrict__ peb1n,
    const float* __restrict__ eemb, const int* __restrict__ lengths)
{
  __shared__ __align__(16) unsigned short W2s[HIDD*HIDD];  // 32 KB, swizzled
  __shared__ __align__(16) char scrS[32768];  // A: pceL (swizzled bf16); B: hL/uL/partU
  __shared__ __align__(16) float PrL[4][HIDD];
  __shared__ __align__(16) float W1dL[HIDD];
  __shared__ float b2L[HIDD];
  __shared__ float pxWL[HIDD];
  __shared__ float xgL[LG][3];
  __shared__ float SxL[3];
  __shared__ float aggAll[4][HIDD];
  __shared__ float xmAll[4][3];
  __shared__ float EFbL[2][HIDD];

  int tt = threadIdx.x;
  int bid = blockIdx.x;
  int g = bid >> 5, ib = bid & 31;
  int i0 = ib*4;
  int nbase = g*LG;

  int w = tt >> 6, l = tt & 63;
  int l15 = l & 15, lg2 = l >> 4;
  int i = i0 + w;
  int ci_blk = (i0 >= 64) ? 1 : 0;   // all 4 i in block share chain

  // stage W2^T -> LDS with XOR swizzle (byte ^= (col&7)<<4)
  {
    int col = tt & 127, kh = tt >> 7;
    const uint4* src = (const uint4*)(w2t + (size_t)col*HIDD + kh*64);
    #pragma unroll
    for (int c8=0;c8<8;++c8) {
      uint4 v = src[c8];
      int koff2 = (kh*64 + c8*8)*2;
      int byteoff = col*256 + (koff2 ^ ((col&7)<<4));
      *(uint4*)((char*)W2s + byteoff) = v;
    }
  }
  // stage pce rows (et baked per-row from block chain) -> scrS, same swizzle
  {
    int r = tt & 127, hh = tt >> 7;
    int et = (ci_blk != ((r >= 64) ? 1 : 0)) ? 1 : 0;
    const uint4* src = (const uint4*)(pceR + ((size_t)(et*NN + nbase + r))*HIDD) + hh*8;
    #pragma unroll
    for (int c8=0;c8<8;++c8) {
      uint4 v = src[c8];
      int koff2 = hh*128 + c8*16;
      int byteoff = r*256 + (koff2 ^ ((r&7)<<4));
      *(uint4*)(scrS + byteoff) = v;
    }
  }
  if (tt < HIDD) {
    W1dL[tt] = peW1l[288*HIDD + tt];
    b2L[tt]  = peb2l[tt];
    pxWL[tt] = pxWl[tt];
  }
  for (int idx=tt; idx<LG*3; idx+=256)
    ((float*)xgL)[idx] = xR[(size_t)nbase*3 + idx];
  for (int idx=l; idx<HIDD; idx+=64)
    PrL[w][idx] = Pr[(size_t)(nbase+i)*HIDD + idx];
  __syncthreads();
  if (tt < 3) {
    float s = 0.f;
    for (int j=0;j<LG;++j) s += xgL[j][tt];
    SxL[tt] = s;
  }
  float pxb0 = pxbl[0];

  // ---- Phase A: wave w handles i = i0+w over all 128 j (4 pairs of 16) ----
  float xi0 = xgL[i][0], xi1 = xgL[i][1], xi2 = xgL[i][2];
  float colsum[8];
  #pragma unroll
  for (int cf=0;cf<8;++cf) colsum[cf] = 0.f;
  float xmx = 0.f, xmy = 0.f, xmz = 0.f;

  for (int jp=0; jp<4; ++jp) {
    int j0 = jp*32 + l15, j1 = j0 + 16;
    float dxa = xi0 - xgL[j0][0], dya = xi1 - xgL[j0][1], dza = xi2 - xgL[j0][2];
    float d2a = dxa*dxa + dya*dya + dza*dza;
    float dxb = xi0 - xgL[j1][0], dyb = xi1 - xgL[j1][1], dzb = xi2 - xgL[j1][2];
    float d2b = dxb*dxb + dyb*dyb + dzb*dzb;

    short8 a0[4], a1[4];
    #pragma unroll
    for (int kk=0;kk<4;++kk) {
      int ks = kk*32 + lg2*8;
      int kbyte = kk*64 + lg2*16;
      f32x4 prA = *(const f32x4*)&PrL[w][ks];
      f32x4 prB = *(const f32x4*)&PrL[w][ks+4];
      f32x4 wdA = *(const f32x4*)&W1dL[ks];
      f32x4 wdB = *(const f32x4*)&W1dL[ks+4];
      uint4 pa = *(const uint4*)(scrS + j0*256 + (kbyte ^ ((j0&7)<<4)));
      uint4 pb = *(const uint4*)(scrS + j1*256 + (kbyte ^ ((j1&7)<<4)));
      a0[kk] = buildA(pa, prA, prB, wdA, wdB, d2a);
      a1[kk] = buildA(pb, prA, prB, wdA, wdB, d2b);
    }

    f32x4 zz = {0.f,0.f,0.f,0.f};
    f32x4 acc[2][8];
    #pragma unroll
    for (int r=0;r<2;++r)
      #pragma unroll
      for (int cf=0;cf<8;++cf) acc[r][cf] = zz;

    #pragma unroll
    for (int kk=0;kk<4;++kk) {
      int kbyte = kk*64 + lg2*16;
      #pragma unroll
      for (int cf=0;cf<8;++cf) {
        int col = cf*16 + l15;
        int boff = col*256 + (kbyte ^ ((col&7)<<4));
        short8 bF = *(const short8*)((const char*)W2s + boff);
        acc[0][cf] = __builtin_amdgcn_mfma_f32_16x16x32_bf16(a0[kk], bF, acc[0][cf], 0,0,0);
        acc[1][cf] = __builtin_amdgcn_mfma_f32_16x16x32_bf16(a1[kk], bF, acc[1][cf], 0,0,0);
      }
    }

    // epilogue: m = relu(acc + b2); colsum[cf] += m; px row-dots -> xm
    float pxp[2][4];
    #pragma unroll
    for (int r=0;r<2;++r)
      #pragma unroll
      for (int q=0;q<4;++q) pxp[r][q] = 0.f;
    #pragma unroll
    for (int cf=0;cf<8;++cf) {
      int col = cf*16 + l15;
      float b2v = b2L[col], pxv = pxWL[col];
      #pragma unroll
      for (int r=0;r<2;++r)
        #pragma unroll
        for (int q=0;q<4;++q) {
          float m = fmaxf(acc[r][cf][q] + b2v, 0.f);
          colsum[cf] += m;
          pxp[r][q] += m * pxv;
        }
    }
    #pragma unroll
    for (int r=0;r<2;++r)
      #pragma unroll
      for (int q=0;q<4;++q) {
        int row = jp*32 + r*16 + lg2*4 + q;   // C/D row mapping (m89)
        float p = pxp[r][q];
        xmx += p*(xi0 - xgL[row][0]);
        xmy += p*(xi1 - xgL[row][1]);
        xmz += p*(xi2 - xgL[row][2]);
      }
  }

  // agg: reduce over lg2 groups (rows), lanes l<16 hold col sums
  #pragma unroll
  for (int cf=0;cf<8;++cf) {
    float v = colsum[cf];
    v += __shfl_xor(v, 16);
    v += __shfl_xor(v, 32);
    if (l < 16) aggAll[w][cf*16 + l15] = v;
  }
  #pragma unroll
  for (int s=1; s<64; s<<=1) {
    xmx += __shfl_xor(xmx, s);
    xmy += __shfl_xor(xmy, s);
    xmz += __shfl_xor(xmz, s);
  }
  if (l == 0) { xmAll[w][0] = xmx; xmAll[w][1] = xmy; xmAll[w][2] = xmz; }

  __syncthreads();   // close phase A: pceL reads done, aggAll/xmAll written

  // ---- Phase B: h-update MLP + x update + next-layer proj ----
  // scrS reused: hL (512 f), uL (512 f), partU (1024 f)
  float* hLp   = (float*)scrS;
  float* uLp   = hLp + 4*HIDD;
  float* partU = uLp + 4*HIDD;
  int c = tt & 127, half = tt >> 7;
  for (int idx=tt; idx<4*HIDD; idx+=256)
    hLp[idx] = hbuf[(size_t)(nbase+i0)*HIDD + idx];
  if (NEXT) {
    int e = half;
    float s = peb1n[c];
    #pragma unroll 8
    for (int k=0;k<32;++k) s += eemb[e*32+k]*peW1n[(256+k)*HIDD+c];
    EFbL[e][c] = s;
  }
  __syncthreads();   // hLp ready

  float p[4];
  // GEMM1: u_pre = [h|agg] @ ph_W1, K=256 split by half
  {
    const float* cat = half ? &aggAll[0][0] : hLp;
    #pragma unroll
    for (int nl=0;nl<4;++nl) p[nl]=0.f;
    const float* Wb = phW1l + (size_t)(half*HIDD)*HIDD + c;
    #pragma unroll 8
    for (int k=0;k<HIDD;++k) {
      float wv = Wb[(size_t)k*HIDD];
      #pragma unroll
      for (int nl=0;nl<4;++nl) p[nl] += cat[nl*HIDD+k]*wv;
    }
    #pragma unroll
    for (int nl=0;nl<4;++nl) partU[(half*4+nl)*HIDD + c] = p[nl];
  }
  __syncthreads();
  #pragma unroll
  for (int q=0;q<2;++q) {
    int nl = half*2+q;
    uLp[nl*HIDD+c] = fmaxf(phb1l[c] + partU[nl*HIDD+c] + partU[(4+nl)*HIDD+c], 0.f);
  }
  __syncthreads();
  // GEMM2: du = u @ ph_W2, K=128 split 64/64
  {
    #pragma unroll
    for (int nl=0;nl<4;++nl) p[nl]=0.f;
    const float* Wb = phW2l + (size_t)(half*64)*HIDD + c;
    #pragma unroll 8
    for (int k=0;k<64;++k) {
      float wv = Wb[(size_t)k*HIDD];
      #pragma unroll
      for (int nl=0;nl<4;++nl) p[nl] += uLp[nl*HIDD + half*64+k]*wv;
    }
    #pragma unroll
    for (int nl=0;nl<4;++nl) partU[(half*4+nl)*HIDD + c] = p[nl];
  }
  __syncthreads();
  #pragma unroll
  for (int q=0;q<2;++q) {
    int nl = half*2+q;
    float hn = hLp[nl*HIDD+c] + phb2l[c] + partU[nl*HIDD+c] + partU[(4+nl)*HIDD+c];
    hLp[nl*HIDD+c] = hn;                                  // in-place update
    hbuf[(size_t)(nbase+i0+nl)*HIDD+c] = hn;
  }
  __syncthreads();
  if (NEXT) {
    const float* W = peW1n + (size_t)half*HIDD*HIDD;
    float a[4];
    #pragma unroll
    for (int nl=0;nl<4;++nl) a[nl]=0.f;
    #pragma unroll 8
    for (int k=0;k<HIDD;++k) {
      float wv = W[k*HIDD+c];
      #pragma unroll
      for (int nl=0;nl<4;++nl) a[nl] += hLp[nl*HIDD+k]*wv;
    }
    if (half == 0) {
      #pragma unroll
      for (int nl=0;nl<4;++nl) Pr[(size_t)(nbase+i0+nl)*HIDD+c] = a[nl];
    } else {
      float e0 = EFbL[0][c], e1 = EFbL[1][c];
      #pragma unroll
      for (int nl=0;nl<4;++nl) {
        pceW[((size_t)(nbase+i0+nl))*HIDD + c]      = f2bf(a[nl] + e0);
        pceW[((size_t)(NN + nbase+i0+nl))*HIDD + c] = f2bf(a[nl] + e1);
      }
    }
  }
  // x update (xm + analytic pxb term), ping-pong write
  if (tt < 12) {
    int nl = tt/3, cc = tt%3;
    int ii = i0 + nl;
    float deg = (float)lengths[g];
    float xmv = xmAll[nl][cc] + pxb0*(128.f*xgL[ii][cc] - SxL[cc]);
    xW[(size_t)(nbase+ii)*3 + cc] = xgL[ii][cc] + xmv/deg;
  }
}

__global__ __launch_bounds__(256) void loss_kernel(
    const float* __restrict__ h, const float* __restrict__ h2iW,
    const float* __restrict__ h2ib, const float* __restrict__ Hn,
    const float* __restrict__ Xn, const float* __restrict__ xf,
    const float* __restrict__ epsH, const float* __restrict__ epsX,
    const int* __restrict__ gmask, float* __restrict__ acc)
{
  __shared__ float hL[8][HIDD];
  __shared__ float rX[256], rH[256], rC[256];
  int tt = threadIdx.x;
  int nb = blockIdx.x*8;
  for (int idx=tt; idx<8*HIDD; idx+=256)
    ((float*)hL)[idx] = h[(size_t)nb*HIDD + idx];
  __syncthreads();
  int nl = tt>>5, c = tt&31;
  int n = nb+nl;
  float mf = gmask[n] ? 1.f : 0.f;
  float pj = h2ib[c];
  #pragma unroll 8
  for (int k=0;k<HIDD;++k) pj += hL[nl][k]*h2iW[k*LATD+c];
  float dH = mf*((pj - Hn[n*LATD+c]) - epsH[n*LATD+c]);
  float sH = dH*dH;
  float sX = 0.f, sc = 0.f;
  if (c < 3) {
    float dX = mf*((xf[n*3+c]-Xn[n*3+c]) - epsX[n*3+c]);
    sX = dX*dX;
  }
  if (c == 0) sc = mf;
  rX[tt]=sX; rH[tt]=sH; rC[tt]=sc;
  __syncthreads();
  for (int s=128; s>0; s>>=1) {
    if (tt<s) { rX[tt]+=rX[tt+s]; rH[tt]+=rH[tt+s]; rC[tt]+=rC[tt+s]; }
    __syncthreads();
  }
  if (tt==0) {
    atomicAdd(&acc[0], rX[0]);
    atomicAdd(&acc[1], rH[0]);
    atomicAdd(&acc[2], rC[0]);
  }
}

__global__ void finalize_kernel(const float* __restrict__ acc, float* __restrict__ out) {
  if (threadIdx.x==0) {
    float cnt = acc[2] + 1e-8f;
    out[0] = acc[0]/cnt;
    out[1] = acc[1]/cnt;
  }
}

extern "C" void kernel_launch(void* const* d_in, const int* in_sizes, int n_in,
                              void* d_out, int out_size, void* d_ws, size_t ws_size,
                              hipStream_t stream) {
  (void)in_sizes; (void)n_in; (void)out_size; (void)ws_size;
  const float* H0    = (const float*)d_in[0];
  const float* X0    = (const float*)d_in[1];
  const float* cond  = (const float*)d_in[2];
  const float* epsH  = (const float*)d_in[3];
  const float* epsX  = (const float*)d_in[4];
  const float* inW1  = (const float*)d_in[5];
  const float* inb1  = (const float*)d_in[6];
  const float* inW2  = (const float*)d_in[7];
  const float* inb2  = (const float*)d_in[8];
  const float* inW3  = (const float*)d_in[9];
  const float* inb3  = (const float*)d_in[10];
  const float* eemb  = (const float*)d_in[11];
  const float* h2iW  = (const float*)d_in[12];
  const float* h2ib  = (const float*)d_in[13];
  const float* peW1  = (const float*)d_in[14];
  const float* peb1  = (const float*)d_in[15];
  const float* peW2  = (const float*)d_in[16];
  const float* peb2  = (const float*)d_in[17];
  const float* phW1  = (const float*)d_in[18];
  const float* phb1  = (const float*)d_in[19];
  const float* phW2  = (const float*)d_in[20];
  const float* phb2  = (const float*)d_in[21];
  const float* pxW   = (const float*)d_in[22];
  const float* pxB   = (const float*)d_in[23];
  const int* gmask   = (const int*)d_in[24];
  const int* batch   = (const int*)d_in[25];
  (void)batch;
  // d_in[26] edges, d_in[27] edge_types: deterministic (dense per-graph meshgrid,
  // et = chain(i)!=chain(j), chain = local>=64) — recomputed on the fly.
  const int* lengths = (const int*)d_in[28];
  const int* tarr    = (const int*)d_in[29];

  float* ws  = (float*)d_ws;
  float* out = (float*)d_out;
  float* Xn   = ws + OFF_XN;
  float* Hn   = ws + OFF_HN;
  unsigned short* w2tb = (unsigned short*)(ws + OFF_W2T);
  float* sabb = ws + OFF_SAB;
  float* tbb  = ws + OFF_TB;
  float* hbuf = ws + OFF_H;
  float* Xa   = ws + OFF_XA;
  float* Xb   = ws + OFF_XB;
  float* Prb  = ws + OFF_PR;
  unsigned short* pce0 = (unsigned short*)(ws + OFF_PCE0);
  unsigned short* pce1 = (unsigned short*)(ws + OFF_PCE1);
  float* accb = ws + OFF_ACC;

  graph_prep_kernel<<<NGRAPH, 128, 0, stream>>>(tarr, inW1, inb1, sabb, tbb, accb);
  noise_kernel<<<(NN*LATD + NN*3 + 255)/256, 256, 0, stream>>>(
      H0, X0, epsH, epsX, gmask, sabb, Hn, Xn, Xa);
  w2t_kernel<<<3, 128, 0, stream>>>(peW2, w2tb);
  node_init_kernel<<<NN/4, 256, 0, stream>>>(
      Hn, cond, tbb, inW1, inW2, inb2, inW3, inb3,
      peW1, peb1, eemb, hbuf, Prb, pce0);

  // l=0: x: Xa->Xb, pce: 0->1 (proj for layer 1)
  layer_kernel<true><<<NGRAPH*32, 256, 0, stream>>>(
      Xa, Xb, Prb, pce0, pce1, w2tb + 0*(size_t)HIDD*HIDD,
      peW1 + 0*(size_t)289*HIDD, peb2 + 0*HIDD, pxW + 0*HIDD, pxB + 0,
      hbuf, phW1 + 0*(size_t)256*HIDD, phb1 + 0*HIDD,
      phW2 + 0*(size_t)HIDD*HIDD, phb2 + 0*HIDD,
      peW1 + 1*(size_t)289*HIDD, peb1 + 1*HIDD, eemb, lengths);
  // l=1: x: Xb->Xa, pce: 1->0 (proj for layer 2)
  layer_kernel<true><<<NGRAPH*32, 256, 0, stream>>>(
      Xb, Xa, Prb, pce1, pce0, w2tb + 1*(size_t)HIDD*HIDD,
      peW1 + 1*(size_t)289*HIDD, peb2 + 1*HIDD, pxW + 1*HIDD, pxB + 1,
      hbuf, phW1 + 1*(size_t)256*HIDD, phb1 + 1*HIDD,
      phW2 + 1*(size_t)HIDD*HIDD, phb2 + 1*HIDD,
      peW1 + 2*(size_t)289*HIDD, peb1 + 2*HIDD, eemb, lengths);
  // l=2: x: Xa->Xb, no next proj
  layer_kernel<false><<<NGRAPH*32, 256, 0, stream>>>(
      Xa, Xb, Prb, pce0, nullptr, w2tb + 2*(size_t)HIDD*HIDD,
      peW1 + 2*(size_t)289*HIDD, peb2 + 2*HIDD, pxW + 2*HIDD, pxB + 2,
      hbuf, phW1 + 2*(size_t)256*HIDD, phb1 + 2*HIDD,
      phW2 + 2*(size_t)HIDD*HIDD, phb2 + 2*HIDD,
      nullptr, nullptr, eemb, lengths);

  loss_kernel<<<NN/8, 256, 0, stream>>>(hbuf, h2iW, h2ib, Hn, Xn, Xb,
                                        epsH, epsX, gmask, accb);
  finalize_kernel<<<1, 64, 0, stream>>>(accb, out);
}